// Round 2
// baseline (1127.891 us; speedup 1.0000x reference)
//
#include <hip/hip_runtime.h>
#include <hip/hip_bf16.h>

// BlockSparseLinear: out[N,OUT] = x[N,IN] . (W * blockmask)^T + bias
// N=8192, IN=4096, OUT=4096, BLOCKSIZE=32, mask (128,128) int32 {0,1}
//
// Round 2: inputs/outputs are FP32 (round-1 NaN = fp32 read as bf16).
// Convert fp32->bf16 at LDS staging time, bf16 MFMA, fp32 accumulate,
// fp32 output. Mask applied at W staging (masked 32-blocks skip the load).

using bf16 = __hip_bfloat16;
typedef __attribute__((ext_vector_type(8))) short short8;   // 8 x bf16 (4 VGPRs)
typedef __attribute__((ext_vector_type(4))) short short4_t; // 4 x bf16 (2 VGPRs)
typedef __attribute__((ext_vector_type(4))) float f32x4;    // MFMA accumulator

#define BM 128          // x-row tile
#define BO 128          // out-feature tile
#define BK 64           // k tile (2 mask blocks)
#define LDK (BK + 8)    // LDS row stride (bf16 elems): 2-way bank alias only (free)

__device__ __forceinline__ short4_t cvt4_bf16(float a, float b, float c, float d) {
    union { short4_t s; bf16 h[4]; } u;
    u.h[0] = __float2bfloat16(a);
    u.h[1] = __float2bfloat16(b);
    u.h[2] = __float2bfloat16(c);
    u.h[3] = __float2bfloat16(d);
    return u.s;
}

__global__ __launch_bounds__(256, 2)
void bsl_mfma_kernel(const float* __restrict__ X,
                     const float* __restrict__ W,
                     const float* __restrict__ bias,
                     const int*  __restrict__ mask,
                     float* __restrict__ out)
{
    const int IN = 4096, OUT = 4096;
    const int KB = IN / 32;           // 128 mask columns

    __shared__ bf16 sA[BM * LDK];
    __shared__ bf16 sB[BO * LDK];

    const int tid  = threadIdx.x;
    const int m0   = blockIdx.x * BM; // 64 tiles
    const int o0   = blockIdx.y * BO; // 32 tiles

    const int wave = tid >> 6;        // 0..3 -> 2x2 wave grid
    const int lane = tid & 63;
    const int wm   = (wave & 1) * 64; // wave m-offset inside tile
    const int wo   = (wave >> 1) * 64;// wave o-offset inside tile

    const int lm = lane & 15;         // fragment row (m or o)
    const int lk = (lane >> 4) * 8;   // fragment k-offset

    f32x4 acc[4][4] = {};             // 64 fp32 accumulators / lane

    for (int k0 = 0; k0 < IN; k0 += BK) {
        // ---- stage A (x): 128x64 fp32 tile -> bf16 LDS; 8 float4 / thread ----
        #pragma unroll
        for (int v = 0; v < 8; ++v) {
            int e   = (v * 256 + tid) * 4;   // element index in tile
            int row = e >> 6;                // /BK
            int col = e & 63;                // %BK (multiple of 4)
            float4 d = *(const float4*)(X + (size_t)(m0 + row) * IN + (k0 + col));
            *(short4_t*)(sA + row * LDK + col) = cvt4_bf16(d.x, d.y, d.z, d.w);
        }
        // ---- stage B (weight), masked per 32-k block; skip load when masked ----
        #pragma unroll
        for (int v = 0; v < 8; ++v) {
            int e   = (v * 256 + tid) * 4;
            int row = e >> 6;
            int col = e & 63;
            int mv  = mask[((o0 + row) >> 5) * KB + ((k0 + col) >> 5)];
            short4_t p = {};
            if (mv != 0) {
                float4 d = *(const float4*)(W + (size_t)(o0 + row) * IN + (k0 + col));
                p = cvt4_bf16(d.x, d.y, d.z, d.w);
            }
            *(short4_t*)(sB + row * LDK + col) = p;
        }
        __syncthreads();

        // ---- MFMA inner loop: 2 k-steps of 32, 4x4 16x16 tiles per wave ----
        #pragma unroll
        for (int kk = 0; kk < BK; kk += 32) {
            short8 af[4], bfr[4];
            #pragma unroll
            for (int i = 0; i < 4; ++i)
                af[i] = *(const short8*)(sA + (wm + i * 16 + lm) * LDK + kk + lk);
            #pragma unroll
            for (int j = 0; j < 4; ++j)
                bfr[j] = *(const short8*)(sB + (wo + j * 16 + lm) * LDK + kk + lk);
            #pragma unroll
            for (int i = 0; i < 4; ++i)
                #pragma unroll
                for (int j = 0; j < 4; ++j)
                    acc[i][j] = __builtin_amdgcn_mfma_f32_16x16x32_bf16(
                        af[i], bfr[j], acc[i][j], 0, 0, 0);
        }
        __syncthreads();
    }

    // ---- epilogue: C/D layout col=lane&15, row=(lane>>4)*4+reg; fp32 out ----
    const int rbase = (lane >> 4) * 4;
    const int ccol  = lane & 15;
    #pragma unroll
    for (int j = 0; j < 4; ++j) {
        int o = o0 + wo + j * 16 + ccol;
        float bv = bias[o];
        #pragma unroll
        for (int i = 0; i < 4; ++i) {
            #pragma unroll
            for (int r = 0; r < 4; ++r) {
                int m = m0 + wm + i * 16 + rbase + r;
                out[(size_t)m * OUT + o] = acc[i][j][r] + bv;
            }
        }
    }
}

extern "C" void kernel_launch(void* const* d_in, const int* in_sizes, int n_in,
                              void* d_out, int out_size, void* d_ws, size_t ws_size,
                              hipStream_t stream) {
    const float* x    = (const float*)d_in[0];   // (8192, 4096) fp32
    const float* w    = (const float*)d_in[1];   // (4096, 4096) fp32
    const float* bias = (const float*)d_in[2];   // (4096,) fp32
    const int*   mask = (const int*)  d_in[3];   // (128, 128) int32
    float* out = (float*)d_out;                  // (8192, 4096) fp32

    dim3 grid(8192 / BM, 4096 / BO);             // (64, 32)
    bsl_mfma_kernel<<<grid, 256, 0, stream>>>(x, w, bias, mask, out);
}

// Round 3
// 549.548 us; speedup vs baseline: 2.0524x; 2.0524x over previous
//
#include <hip/hip_runtime.h>
#include <hip/hip_bf16.h>

// BlockSparseLinear: out[N,OUT] = x[N,IN] . (W * blockmask)^T + bias
// N=8192, IN=4096, OUT=4096, BLOCKSIZE=32, mask (128,128) int32 {0,1}
//
// Round 3: three-pass.
//   P1: X fp32 -> bf16 into ws          (memory-bound, ~25 us)
//   P2: W fp32 -> bf16 masked into ws   (masked blocks: skip HBM read, write 0)
//   P3: m97-structure bf16 GEMM-BT: 128x128 tile, BK=64,
//       global_load_lds width=16 staging, 16x16x32 MFMA,
//       per-(j,kk) wave-uniform mask skip (MFMA K=32 == mask block size).
// Fallback: round-2 single-pass kernel if ws_size < 101 MB.

using bf16 = __hip_bfloat16;
typedef __attribute__((ext_vector_type(8))) short short8;   // 8 x bf16 (4 VGPRs)
typedef __attribute__((ext_vector_type(4))) short short4_t; // 4 x bf16
typedef __attribute__((ext_vector_type(4))) float f32x4;    // MFMA accumulator

#define N_ROWS 8192
#define IN     4096
#define OUT    4096
#define KB     128      // mask cols (IN/32)

#define BM 128
#define BO 128
#define BK 64

__device__ __forceinline__ short4_t cvt4_bf16(float a, float b, float c, float d) {
    union { short4_t s; bf16 h[4]; } u;
    u.h[0] = __float2bfloat16(a);
    u.h[1] = __float2bfloat16(b);
    u.h[2] = __float2bfloat16(c);
    u.h[3] = __float2bfloat16(d);
    return u.s;
}

// ---------------- Pass 1: X fp32 -> bf16 ----------------
__global__ __launch_bounds__(256)
void cvt_x_kernel(const float* __restrict__ X, bf16* __restrict__ Xb) {
    size_t i = ((size_t)blockIdx.x * 256 + threadIdx.x) * 4;
    float4 d = *(const float4*)(X + i);
    *(short4_t*)(Xb + i) = cvt4_bf16(d.x, d.y, d.z, d.w);
}

// ---------------- Pass 2: W fp32 -> bf16, masked ----------------
__global__ __launch_bounds__(256)
void cvt_w_kernel(const float* __restrict__ W, const int* __restrict__ mask,
                  bf16* __restrict__ Wb) {
    size_t i = ((size_t)blockIdx.x * 256 + threadIdx.x) * 4;
    int row = (int)(i >> 12);          // /IN
    int col = (int)(i & 4095);         // %IN  (4 elems stay in one 32-block)
    int mv  = mask[(row >> 5) * KB + (col >> 5)];
    short4_t p = {};
    if (mv != 0) {
        float4 d = *(const float4*)(W + i);
        p = cvt4_bf16(d.x, d.y, d.z, d.w);
    }
    *(short4_t*)(Wb + i) = p;
}

// ---------------- Pass 3: bf16 GEMM-BT with mask skip ----------------
__global__ __launch_bounds__(256)
void bsl_gemm_kernel(const bf16* __restrict__ Xb, const bf16* __restrict__ Wb,
                     const float* __restrict__ bias, const int* __restrict__ mask,
                     float* __restrict__ out)
{
    // NOTE: no LDS padding — global_load_lds dest is wave-uniform base + lane*16.
    __shared__ bf16 sA[BM * BK];   // 16 KB
    __shared__ bf16 sB[BO * BK];   // 16 KB
    __shared__ int  sMask[4 * KB]; // mask rows for this o-tile (4 rows x 128)

    const int tid  = threadIdx.x;
    const int m0   = blockIdx.x * BM;
    const int o0   = blockIdx.y * BO;
    const int wave = tid >> 6;
    const int lane = tid & 63;
    const int wm   = (wave & 1) * 64;
    const int wo   = (wave >> 1) * 64;

    const int lm = lane & 15;          // fragment row
    const int lk = (lane >> 4) * 8;    // fragment k-offset

    // staging geometry: one wave issue = 64 lanes x 16B = 8 rows x 64 cols (bf16)
    const int srow = lane >> 3;        // 0..7
    const int scol = (lane & 7) * 8;   // 0..56

    // mask rows (o0>>5 .. +3), contiguous: mask[(o0>>5)*128 + t] = mask[o0*4 + t]
    for (int t = tid; t < 4 * KB; t += 256)
        sMask[t] = mask[o0 * 4 + t];

    f32x4 acc[4][4] = {};

    for (int k0 = 0; k0 < IN; k0 += BK) {
        // ---- async stage A and B: 4 issues per wave each ----
        #pragma unroll
        for (int v = 0; v < 4; ++v) {
            int r = wave * 32 + v * 8;
            __builtin_amdgcn_global_load_lds(
                (const __attribute__((address_space(1))) void*)
                    (Xb + (size_t)(m0 + r + srow) * IN + k0 + scol),
                (__attribute__((address_space(3))) void*)(sA + r * BK),
                16, 0, 0);
        }
        #pragma unroll
        for (int v = 0; v < 4; ++v) {
            int r = wave * 32 + v * 8;
            __builtin_amdgcn_global_load_lds(
                (const __attribute__((address_space(1))) void*)
                    (Wb + (size_t)(o0 + r + srow) * IN + k0 + scol),
                (__attribute__((address_space(3))) void*)(sB + r * BK),
                16, 0, 0);
        }
        __syncthreads();   // compiler emits vmcnt(0) drain here (m97 structure)

        const int c0 = k0 >> 5;        // mask col of kk=0
        #pragma unroll
        for (int kk = 0; kk < 2; ++kk) {
            short8 af[4];
            #pragma unroll
            for (int i = 0; i < 4; ++i)
                af[i] = *(const short8*)(sA + (wm + i * 16 + lm) * BK + kk * 32 + lk);
            #pragma unroll
            for (int j = 0; j < 4; ++j) {
                // 16-row B tile sits in exactly one mask row; K=32 in one mask col
                int mv = sMask[((wo >> 5) + (j >> 1)) * KB + c0 + kk];
                if (mv != 0) {   // wave-uniform branch
                    short8 bfr = *(const short8*)(sB + (wo + j * 16 + lm) * BK + kk * 32 + lk);
                    #pragma unroll
                    for (int i = 0; i < 4; ++i)
                        acc[i][j] = __builtin_amdgcn_mfma_f32_16x16x32_bf16(
                            af[i], bfr, acc[i][j], 0, 0, 0);
                }
            }
        }
        __syncthreads();
    }

    // ---- epilogue: C/D layout col=lane&15, row=(lane>>4)*4+reg; fp32 out ----
    const int rbase = (lane >> 4) * 4;
    const int ccol  = lane & 15;
    #pragma unroll
    for (int j = 0; j < 4; ++j) {
        int o = o0 + wo + j * 16 + ccol;
        float bv = bias[o];
        #pragma unroll
        for (int i = 0; i < 4; ++i) {
            #pragma unroll
            for (int r = 0; r < 4; ++r) {
                int m = m0 + wm + i * 16 + rbase + r;
                out[(size_t)m * OUT + o] = acc[i][j][r] + bv;
            }
        }
    }
}

// ---------------- Fallback (round-2 single-pass, known-good) ----------------
#define LDK (BK + 8)
__global__ __launch_bounds__(256, 2)
void bsl_fallback_kernel(const float* __restrict__ X, const float* __restrict__ W,
                         const float* __restrict__ bias, const int* __restrict__ mask,
                         float* __restrict__ out)
{
    __shared__ bf16 sA[BM * LDK];
    __shared__ bf16 sB[BO * LDK];
    const int tid = threadIdx.x;
    const int m0 = blockIdx.x * BM, o0 = blockIdx.y * BO;
    const int wave = tid >> 6, lane = tid & 63;
    const int wm = (wave & 1) * 64, wo = (wave >> 1) * 64;
    const int lm = lane & 15, lk = (lane >> 4) * 8;
    f32x4 acc[4][4] = {};
    for (int k0 = 0; k0 < IN; k0 += BK) {
        #pragma unroll
        for (int v = 0; v < 8; ++v) {
            int e = (v * 256 + tid) * 4, row = e >> 6, col = e & 63;
            float4 d = *(const float4*)(X + (size_t)(m0 + row) * IN + (k0 + col));
            *(short4_t*)(sA + row * LDK + col) = cvt4_bf16(d.x, d.y, d.z, d.w);
        }
        #pragma unroll
        for (int v = 0; v < 8; ++v) {
            int e = (v * 256 + tid) * 4, row = e >> 6, col = e & 63;
            int mv = mask[((o0 + row) >> 5) * KB + ((k0 + col) >> 5)];
            short4_t p = {};
            if (mv != 0) {
                float4 d = *(const float4*)(W + (size_t)(o0 + row) * IN + (k0 + col));
                p = cvt4_bf16(d.x, d.y, d.z, d.w);
            }
            *(short4_t*)(sB + row * LDK + col) = p;
        }
        __syncthreads();
        #pragma unroll
        for (int kk = 0; kk < BK; kk += 32) {
            short8 af[4], bfr[4];
            #pragma unroll
            for (int i = 0; i < 4; ++i)
                af[i] = *(const short8*)(sA + (wm + i * 16 + lm) * LDK + kk + lk);
            #pragma unroll
            for (int j = 0; j < 4; ++j)
                bfr[j] = *(const short8*)(sB + (wo + j * 16 + lm) * LDK + kk + lk);
            #pragma unroll
            for (int i = 0; i < 4; ++i)
                #pragma unroll
                for (int j = 0; j < 4; ++j)
                    acc[i][j] = __builtin_amdgcn_mfma_f32_16x16x32_bf16(
                        af[i], bfr[j], acc[i][j], 0, 0, 0);
        }
        __syncthreads();
    }
    const int rbase = (lane >> 4) * 4, ccol = lane & 15;
    #pragma unroll
    for (int j = 0; j < 4; ++j) {
        int o = o0 + wo + j * 16 + ccol;
        float bv = bias[o];
        #pragma unroll
        for (int i = 0; i < 4; ++i)
            #pragma unroll
            for (int r = 0; r < 4; ++r)
                out[(size_t)(m0 + wm + i * 16 + rbase + r) * OUT + o] = acc[i][j][r] + bv;
    }
}

extern "C" void kernel_launch(void* const* d_in, const int* in_sizes, int n_in,
                              void* d_out, int out_size, void* d_ws, size_t ws_size,
                              hipStream_t stream) {
    const float* x    = (const float*)d_in[0];   // (8192, 4096) fp32
    const float* w    = (const float*)d_in[1];   // (4096, 4096) fp32
    const float* bias = (const float*)d_in[2];   // (4096,) fp32
    const int*   mask = (const int*)  d_in[3];   // (128, 128) int32
    float* out = (float*)d_out;                  // (8192, 4096) fp32

    const size_t xb_bytes = (size_t)N_ROWS * IN * sizeof(bf16);  // 67,108,864
    const size_t wb_bytes = (size_t)OUT * IN * sizeof(bf16);     // 33,554,432

    if (ws_size >= xb_bytes + wb_bytes) {
        bf16* xb = (bf16*)d_ws;
        bf16* wb = (bf16*)((char*)d_ws + xb_bytes);
        cvt_x_kernel<<<(N_ROWS * (size_t)IN) / (256 * 4), 256, 0, stream>>>(x, xb);
        cvt_w_kernel<<<(OUT * (size_t)IN) / (256 * 4), 256, 0, stream>>>(w, mask, wb);
        dim3 grid(N_ROWS / BM, OUT / BO);        // (64, 32)
        bsl_gemm_kernel<<<grid, 256, 0, stream>>>(xb, wb, bias, mask, out);
    } else {
        dim3 grid(N_ROWS / BM, OUT / BO);
        bsl_fallback_kernel<<<grid, 256, 0, stream>>>(x, w, bias, mask, out);
    }
}

// Round 4
// 487.220 us; speedup vs baseline: 2.3150x; 1.1279x over previous
//
#include <hip/hip_runtime.h>
#include <hip/hip_bf16.h>

// BlockSparseLinear: out[N,OUT] = x[N,IN] . (W * blockmask)^T + bias
// N=8192, IN=4096, OUT=4096, BLOCKSIZE=32, mask (128,128) int32 {0,1}
//
// Round 4: round-3 structure + XOR-swizzled LDS (kills the 16-way bank
// conflicts caused by the unpadded 128-B row stride that global_load_lds
// requires), masked-B staging skip, masked-kk skip, fused convert pass.

using bf16 = __hip_bfloat16;
typedef __attribute__((ext_vector_type(8))) short short8;   // 8 x bf16 (4 VGPRs)
typedef __attribute__((ext_vector_type(4))) short short4_t; // 4 x bf16
typedef __attribute__((ext_vector_type(4))) float f32x4;    // MFMA accumulator

#define N_ROWS 8192
#define IN     4096
#define OUT    4096
#define KB     128      // mask cols (IN/32)

#define BM 128
#define BO 128
#define BK 64           // row = 8 chunks of 8 bf16 (16 B each)

__device__ __forceinline__ short4_t cvt4_bf16(float a, float b, float c, float d) {
    union { short4_t s; bf16 h[4]; } u;
    u.h[0] = __float2bfloat16(a);
    u.h[1] = __float2bfloat16(b);
    u.h[2] = __float2bfloat16(c);
    u.h[3] = __float2bfloat16(d);
    return u.s;
}

// ---------------- Fused convert: X fp32->bf16 ; W fp32->bf16 masked ----------
// blocks [0, 32768): X ; blocks [32768, 49152): W
__global__ __launch_bounds__(256)
void cvt_kernel(const float* __restrict__ X, const float* __restrict__ W,
                const int* __restrict__ mask,
                bf16* __restrict__ Xb, bf16* __restrict__ Wb) {
    int b = blockIdx.x;
    if (b < 32768) {
        size_t i = ((size_t)b * 256 + threadIdx.x) * 4;
        float4 d = *(const float4*)(X + i);
        *(short4_t*)(Xb + i) = cvt4_bf16(d.x, d.y, d.z, d.w);
    } else {
        size_t i = ((size_t)(b - 32768) * 256 + threadIdx.x) * 4;
        int row = (int)(i >> 12);          // /IN
        int col = (int)(i & 4095);         // %IN (4 elems in one 32-block)
        int mv  = mask[(row >> 5) * KB + (col >> 5)];
        short4_t p = {};
        if (mv != 0) {
            float4 d = *(const float4*)(W + i);
            p = cvt4_bf16(d.x, d.y, d.z, d.w);
        }
        *(short4_t*)(Wb + i) = p;
    }
}

// ---------------- bf16 GEMM-BT, swizzled LDS, mask skip ----------------
__global__ __launch_bounds__(256)
void bsl_gemm_kernel(const bf16* __restrict__ Xb, const bf16* __restrict__ Wb,
                     const float* __restrict__ bias, const int* __restrict__ mask,
                     float* __restrict__ out)
{
    // Swizzled layout: chunk j (16 B) of row r lives at slot (j ^ (r&7)).
    __shared__ bf16 sA[BM * BK];   // 16 KB
    __shared__ bf16 sB[BO * BK];   // 16 KB
    __shared__ int  sMask[4 * KB]; // 4 mask rows x 128 cols for this o-tile

    const int tid  = threadIdx.x;
    const int m0   = blockIdx.x * BM;
    const int o0   = blockIdx.y * BO;
    const int wave = tid >> 6;
    const int lane = tid & 63;
    const int wm   = (wave & 1) * 64;
    const int wo   = (wave >> 1) * 64;

    const int lm = lane & 15;          // fragment row
    const int q  = lane >> 4;          // 0..3 -> k chunk within 32
    const int xm = lm & 7;             // read-side swizzle xor

    // staging geometry: one issue = 8 rows x 8 chunks; lane -> (srow, slot)
    const int srow = lane >> 3;                      // 0..7
    const int scol = ((lane & 7) ^ srow) * 8;        // swizzled source chunk

    for (int t = tid; t < 4 * KB; t += 256)
        sMask[t] = mask[o0 * 4 + t];
    __syncthreads();                   // staging reads sMask below

    f32x4 acc[4][4] = {};

    for (int k0 = 0; k0 < IN; k0 += BK) {
        const int c0 = k0 >> 5;        // first mask col of this k-tile
        // ---- stage A: 4 issues/wave ----
        #pragma unroll
        for (int v = 0; v < 4; ++v) {
            int r = wave * 32 + v * 8;
            __builtin_amdgcn_global_load_lds(
                (const __attribute__((address_space(1))) void*)
                    (Xb + (size_t)(m0 + r + srow) * IN + k0 + scol),
                (__attribute__((address_space(3))) void*)(sA + r * BK),
                16, 0, 0);
        }
        // ---- stage B: skip issue when both mask cols are zero (never read) ----
        const int bm2 = sMask[wave * KB + c0] | sMask[wave * KB + c0 + 1];
        if (bm2 != 0) {
            #pragma unroll
            for (int v = 0; v < 4; ++v) {
                int r = wave * 32 + v * 8;
                __builtin_amdgcn_global_load_lds(
                    (const __attribute__((address_space(1))) void*)
                        (Wb + (size_t)(o0 + r + srow) * IN + k0 + scol),
                    (__attribute__((address_space(3))) void*)(sB + r * BK),
                    16, 0, 0);
            }
        }
        __syncthreads();

        #pragma unroll
        for (int kk = 0; kk < 2; ++kk) {
            const int mr  = wo >> 5;
            const int mv0 = sMask[mr * KB + c0 + kk];        // j = 0,1
            const int mv1 = sMask[(mr + 1) * KB + c0 + kk];  // j = 2,3
            if ((mv0 | mv1) == 0) continue;   // wave-uniform

            short8 af[4];
            #pragma unroll
            for (int i = 0; i < 4; ++i) {
                int R = wm + i * 16 + lm;
                af[i] = *(const short8*)(sA + R * BK + (((kk * 4 + q) ^ xm) * 8));
            }
            #pragma unroll
            for (int j = 0; j < 4; ++j) {
                int mv = (j < 2) ? mv0 : mv1;
                if (mv != 0) {
                    int R = wo + j * 16 + lm;
                    short8 bfr = *(const short8*)(sB + R * BK + (((kk * 4 + q) ^ xm) * 8));
                    #pragma unroll
                    for (int i = 0; i < 4; ++i)
                        acc[i][j] = __builtin_amdgcn_mfma_f32_16x16x32_bf16(
                            af[i], bfr, acc[i][j], 0, 0, 0);
                }
            }
        }
        __syncthreads();
    }

    // ---- epilogue: C/D layout col=lane&15, row=(lane>>4)*4+reg; fp32 out ----
    const int rbase = (lane >> 4) * 4;
    const int ccol  = lane & 15;
    #pragma unroll
    for (int j = 0; j < 4; ++j) {
        int o = o0 + wo + j * 16 + ccol;
        float bv = bias[o];
        #pragma unroll
        for (int i = 0; i < 4; ++i) {
            #pragma unroll
            for (int r = 0; r < 4; ++r) {
                int m = m0 + wm + i * 16 + rbase + r;
                out[(size_t)m * OUT + o] = acc[i][j][r] + bv;
            }
        }
    }
}

// ---------------- Fallback (round-2 single-pass, known-good) ----------------
#define LDK (BK + 8)
__global__ __launch_bounds__(256, 2)
void bsl_fallback_kernel(const float* __restrict__ X, const float* __restrict__ W,
                         const float* __restrict__ bias, const int* __restrict__ mask,
                         float* __restrict__ out)
{
    __shared__ bf16 sA[BM * LDK];
    __shared__ bf16 sB[BO * LDK];
    const int tid = threadIdx.x;
    const int m0 = blockIdx.x * BM, o0 = blockIdx.y * BO;
    const int wave = tid >> 6, lane = tid & 63;
    const int wm = (wave & 1) * 64, wo = (wave >> 1) * 64;
    const int lm = lane & 15, lk = (lane >> 4) * 8;
    f32x4 acc[4][4] = {};
    for (int k0 = 0; k0 < IN; k0 += BK) {
        #pragma unroll
        for (int v = 0; v < 8; ++v) {
            int e = (v * 256 + tid) * 4, row = e >> 6, col = e & 63;
            float4 d = *(const float4*)(X + (size_t)(m0 + row) * IN + (k0 + col));
            *(short4_t*)(sA + row * LDK + col) = cvt4_bf16(d.x, d.y, d.z, d.w);
        }
        #pragma unroll
        for (int v = 0; v < 8; ++v) {
            int e = (v * 256 + tid) * 4, row = e >> 6, col = e & 63;
            int mv = mask[((o0 + row) >> 5) * KB + ((k0 + col) >> 5)];
            short4_t p = {};
            if (mv != 0) {
                float4 d = *(const float4*)(W + (size_t)(o0 + row) * IN + (k0 + col));
                p = cvt4_bf16(d.x, d.y, d.z, d.w);
            }
            *(short4_t*)(sB + row * LDK + col) = p;
        }
        __syncthreads();
        #pragma unroll
        for (int kk = 0; kk < BK; kk += 32) {
            short8 af[4], bfr[4];
            #pragma unroll
            for (int i = 0; i < 4; ++i)
                af[i] = *(const short8*)(sA + (wm + i * 16 + lm) * LDK + kk + lk);
            #pragma unroll
            for (int j = 0; j < 4; ++j)
                bfr[j] = *(const short8*)(sB + (wo + j * 16 + lm) * LDK + kk + lk);
            #pragma unroll
            for (int i = 0; i < 4; ++i)
                #pragma unroll
                for (int j = 0; j < 4; ++j)
                    acc[i][j] = __builtin_amdgcn_mfma_f32_16x16x32_bf16(
                        af[i], bfr[j], acc[i][j], 0, 0, 0);
        }
        __syncthreads();
    }
    const int rbase = (lane >> 4) * 4, ccol = lane & 15;
    #pragma unroll
    for (int j = 0; j < 4; ++j) {
        int o = o0 + wo + j * 16 + ccol;
        float bv = bias[o];
        #pragma unroll
        for (int i = 0; i < 4; ++i)
            #pragma unroll
            for (int r = 0; r < 4; ++r)
                out[(size_t)(m0 + wm + i * 16 + rbase + r) * OUT + o] = acc[i][j][r] + bv;
    }
}

extern "C" void kernel_launch(void* const* d_in, const int* in_sizes, int n_in,
                              void* d_out, int out_size, void* d_ws, size_t ws_size,
                              hipStream_t stream) {
    const float* x    = (const float*)d_in[0];   // (8192, 4096) fp32
    const float* w    = (const float*)d_in[1];   // (4096, 4096) fp32
    const float* bias = (const float*)d_in[2];   // (4096,) fp32
    const int*   mask = (const int*)  d_in[3];   // (128, 128) int32
    float* out = (float*)d_out;                  // (8192, 4096) fp32

    const size_t xb_bytes = (size_t)N_ROWS * IN * sizeof(bf16);  // 67,108,864
    const size_t wb_bytes = (size_t)OUT * IN * sizeof(bf16);     // 33,554,432

    if (ws_size >= xb_bytes + wb_bytes) {
        bf16* xb = (bf16*)d_ws;
        bf16* wb = (bf16*)((char*)d_ws + xb_bytes);
        const int xblk = (int)((N_ROWS * (size_t)IN) / 1024);    // 32768
        const int wblk = (int)((OUT * (size_t)IN) / 1024);       // 16384
        cvt_kernel<<<xblk + wblk, 256, 0, stream>>>(x, w, mask, xb, wb);
        dim3 grid(N_ROWS / BM, OUT / BO);        // (64, 32)
        bsl_gemm_kernel<<<grid, 256, 0, stream>>>(xb, wb, bias, mask, out);
    } else {
        dim3 grid(N_ROWS / BM, OUT / BO);
        bsl_fallback_kernel<<<grid, 256, 0, stream>>>(x, w, bias, mask, out);
    }
}